// Round 1
// baseline (212.581 us; speedup 1.0000x reference)
//
#include <hip/hip_runtime.h>
#include <hip/hip_bf16.h>

// ProbsNet: out = mean over 5 of [p_m @ tmp_{0 or 1}]
//   tmp_t[i] = sum_d sigmoid(pB*(pBEV*BEV + ST_t[i,d])) * W_t[i,d]
//   p_m = 84-entry softmax expansion of probs_m (4 logits)
// Memory-bound: 176 MB of fp32 streamed once.

#define D_DIM   131072
#define N_ROWS  84
#define CHUNKS  8
#define CHUNK   (D_DIM / CHUNKS)   // 16384 floats per block

// entry t of calc_probs(logits): i=t/21; r=t%21
//   r==0 -> p_i ; else r-=1, j=r/5, s=r%5: s==0 -> p_i*p_j else p_i*p_j*p_{s-1}
__device__ inline float prob_entry(const float* __restrict__ logits, int t) {
    float l0 = logits[0], l1 = logits[1], l2 = logits[2], l3 = logits[3];
    float m  = fmaxf(fmaxf(l0, l1), fmaxf(l2, l3));
    float e0 = __expf(l0 - m), e1 = __expf(l1 - m);
    float e2 = __expf(l2 - m), e3 = __expf(l3 - m);
    float inv = 1.0f / (e0 + e1 + e2 + e3);
    float p[4] = {e0 * inv, e1 * inv, e2 * inv, e3 * inv};
    int i = t / 21;
    int r = t - i * 21;
    if (r == 0) return p[i];
    r -= 1;
    int j = r / 5;
    int s = r - j * 5;
    float v = p[i] * p[j];
    return (s == 0) ? v : v * p[s - 1];
}

__global__ __launch_bounds__(256) void probsnet_kernel(
    const float* __restrict__ BEV,
    const float* __restrict__ ST0, const float* __restrict__ W0,
    const float* __restrict__ ST1, const float* __restrict__ W1,
    const float* __restrict__ probs0, const float* __restrict__ probs1,
    const float* __restrict__ probs2, const float* __restrict__ probs3,
    const float* __restrict__ probs4,
    const float* __restrict__ pBEV, const float* __restrict__ pB,
    float* __restrict__ out)
{
    const int bid    = blockIdx.x;
    const int tensor = bid / (N_ROWS * CHUNKS);          // 0 or 1
    const int rem    = bid - tensor * (N_ROWS * CHUNKS);
    const int row    = rem / CHUNKS;
    const int chunk  = rem - row * CHUNKS;

    const float bev = pBEV[0] * BEV[0];
    const float pb  = pB[0];

    const size_t base = (size_t)row * D_DIM + (size_t)chunk * CHUNK;
    const float* __restrict__ st = (tensor == 0 ? ST0 : ST1) + base;
    const float* __restrict__ w  = (tensor == 0 ? W0  : W1 ) + base;

    float acc = 0.0f;
    const int t = threadIdx.x;
    // 16384 floats / (256 threads * 4) = 16 iterations, float4 coalesced
    #pragma unroll
    for (int i = 0; i < CHUNK / (256 * 4); ++i) {
        const int idx = (i * 256 + t) * 4;
        float4 s4 = *(const float4*)(st + idx);
        float4 w4 = *(const float4*)(w  + idx);
        float sg;
        sg = 1.0f / (1.0f + __expf(-pb * (bev + s4.x))); acc += sg * w4.x;
        sg = 1.0f / (1.0f + __expf(-pb * (bev + s4.y))); acc += sg * w4.y;
        sg = 1.0f / (1.0f + __expf(-pb * (bev + s4.z))); acc += sg * w4.z;
        sg = 1.0f / (1.0f + __expf(-pb * (bev + s4.w))); acc += sg * w4.w;
    }

    // wave64 shuffle reduction
    #pragma unroll
    for (int off = 32; off > 0; off >>= 1)
        acc += __shfl_down(acc, off, 64);

    __shared__ float red[4];
    const int wave = threadIdx.x >> 6;
    const int lane = threadIdx.x & 63;
    if (lane == 0) red[wave] = acc;
    __syncthreads();

    if (threadIdx.x == 0) {
        float bs = red[0] + red[1] + red[2] + red[3];
        float pw;
        if (tensor == 0) {
            pw = prob_entry(probs0, row);
        } else {
            pw = prob_entry(probs1, row) + prob_entry(probs2, row)
               + prob_entry(probs3, row) + prob_entry(probs4, row);
        }
        atomicAdd(out, bs * pw * 0.2f);
    }
}

extern "C" void kernel_launch(void* const* d_in, const int* in_sizes, int n_in,
                              void* d_out, int out_size, void* d_ws, size_t ws_size,
                              hipStream_t stream) {
    // setup_inputs order:
    // 0=BEV(1) 1=ST0 2=Weight0 3=ST1 4=Weight1 5=Problem(int,unused)
    // 6..10=probs0..probs4(4) 11=pBEV(1) 12=pB(1)
    const float* BEV    = (const float*)d_in[0];
    const float* ST0    = (const float*)d_in[1];
    const float* W0     = (const float*)d_in[2];
    const float* ST1    = (const float*)d_in[3];
    const float* W1     = (const float*)d_in[4];
    const float* probs0 = (const float*)d_in[6];
    const float* probs1 = (const float*)d_in[7];
    const float* probs2 = (const float*)d_in[8];
    const float* probs3 = (const float*)d_in[9];
    const float* probs4 = (const float*)d_in[10];
    const float* pBEV   = (const float*)d_in[11];
    const float* pB     = (const float*)d_in[12];
    float* out = (float*)d_out;

    // d_out is re-poisoned to 0xAA before every timed launch — zero it first.
    hipMemsetAsync(out, 0, sizeof(float), stream);

    const int grid = 2 * N_ROWS * CHUNKS;  // 1344 blocks
    probsnet_kernel<<<grid, 256, 0, stream>>>(
        BEV, ST0, W0, ST1, W1,
        probs0, probs1, probs2, probs3, probs4,
        pBEV, pB, out);
}